// Round 1
// baseline (19023.076 us; speedup 1.0000x reference)
//
#include <hip/hip_runtime.h>
#include <hip/hip_bf16.h>
#include <stdint.h>

typedef unsigned int u32;
typedef unsigned long long u64;
typedef __attribute__((ext_vector_type(8))) short short8;
typedef __attribute__((ext_vector_type(4))) float floatx4;

#define T_STEPS 4096
#define BATCH   15
#define N_IN    512
#define N_H     1024
#define G_SCAN  16          // scan workgroups, 64 cols each
#define HTAG_WORDS (15*512) // tagged words per h buffer (15 batches x 512 pairs)

// ---------- ws layout (bytes) ----------
// xp   : u64[T*64*64]            = 128 MiB   (bf16x4 per lane, MFMA C-frag order)
// wihb : u32[1024*256]           = 1 MiB     (W_ih as packed bf16 pairs)
// htag : u64[2][HTAG_WORDS]      = 120 KiB   (tagged h broadcast, ping-pong)
#define OFF_XP   0
#define OFF_WIHB (134217728)
#define OFF_HTAG (134217728 + 1048576)

__device__ inline u32 f2bf1(float f) {            // fp32 -> bf16 (RNE), as u32
    u32 u = __builtin_bit_cast(u32, f);
    return (u + 0x7FFFu + ((u >> 16) & 1u)) >> 16;
}
__device__ inline float bf2f(u32 us) {            // bf16 (low 16) -> fp32
    return __builtin_bit_cast(float, us << 16);
}
__device__ inline float tanh_fast(float x) {
    float e = __expf(2.0f * x);                   // inf-safe at both ends
    return 1.0f - 2.0f / (e + 1.0f);
}

// ---------------- kernel 0: convert W_ih to packed bf16 ----------------
__global__ void k_cvt_wih(const float* __restrict__ W_ih, u32* __restrict__ wihb) {
    int row = blockIdx.x;                  // 0..1023
    int tid = threadIdx.x;                 // 0..255, 2 elems each
    const float* p = W_ih + (size_t)row * N_IN + tid * 2;
    u32 packed = f2bf1(p[0]) | (f2bf1(p[1]) << 16);
    wihb[row * (N_IN / 2) + tid] = packed;
}

// ---------------- kernel 1: x_proj GEMM ----------------
// grid (T_STEPS, 4); block 256. Wave w covers cols [slice*256 + w*64, +64).
// Output xp in MFMA C-frag order: xp[((t*64 + cw)*64 + lane)] = bf16x4 (rows quad*4+i, col cw*16+(l&15))
__global__ void __launch_bounds__(256) k_xproj(
        const float* __restrict__ x, const u32* __restrict__ wihb,
        const float* __restrict__ b_ih, const float* __restrict__ b_hh,
        u64* __restrict__ xp) {
    const int t     = blockIdx.x;
    const int slice = blockIdx.y;
    const int tid   = threadIdx.x;
    const int wave  = tid >> 6;
    const int l     = tid & 63;
    const int row   = l & 15;       // batch
    const int quad  = l >> 4;
    const int colbase = slice * 256 + wave * 64;

    floatx4 acc[4] = {{0,0,0,0},{0,0,0,0},{0,0,0,0},{0,0,0,0}};
    const float* xrow = x + ((size_t)row * T_STEPS + t) * N_IN;   // only valid for row<15

    #pragma unroll
    for (int kk = 0; kk < 16; ++kk) {
        short8 a;
        if (row < 15) {
            const float* pa = xrow + kk * 32 + quad * 8;
            float4 x0 = *(const float4*)(pa);
            float4 x1 = *(const float4*)(pa + 4);
            a[0]=(short)f2bf1(x0.x); a[1]=(short)f2bf1(x0.y); a[2]=(short)f2bf1(x0.z); a[3]=(short)f2bf1(x0.w);
            a[4]=(short)f2bf1(x1.x); a[5]=(short)f2bf1(x1.y); a[6]=(short)f2bf1(x1.z); a[7]=(short)f2bf1(x1.w);
        } else {
            #pragma unroll
            for (int j = 0; j < 8; ++j) a[j] = 0;
        }
        #pragma unroll
        for (int c4 = 0; c4 < 4; ++c4) {
            int col = colbase + c4 * 16 + (l & 15);
            const uint4* pb = (const uint4*)(wihb + (size_t)col * (N_IN/2) + kk * 16 + quad * 4);
            short8 b = __builtin_bit_cast(short8, *pb);
            acc[c4] = __builtin_amdgcn_mfma_f32_16x16x32_bf16(a, b, acc[c4], 0, 0, 0);
        }
    }
    #pragma unroll
    for (int c4 = 0; c4 < 4; ++c4) {
        int col = colbase + c4 * 16 + (l & 15);
        float bias = b_ih[col] + b_hh[col];
        u64 packed = (u64)f2bf1(acc[c4][0] + bias)
                   | ((u64)f2bf1(acc[c4][1] + bias) << 16)
                   | ((u64)f2bf1(acc[c4][2] + bias) << 32)
                   | ((u64)f2bf1(acc[c4][3] + bias) << 48);
        int cw = slice * 16 + wave * 4 + c4;
        xp[((size_t)t * 64 + cw) * 64 + l] = packed;
    }
}

// ---------------- kernel 2: sequential scan (persistent, 16 WGs) ----------------
#define LDS_ROW 516   // u32 per h row: 512 + 4 pad (8 bf16) -> bank-spread for b128 reads

__device__ inline bool poll_stage(const u64* __restrict__ buf, u32 tag, int tid,
                                  u32* __restrict__ h_lds) {
    u32 got = 0;
    int guard = 0;
    while (got != 0x3FFFFFFFu) {
        u64 v[30];
        #pragma unroll
        for (int i = 0; i < 30; ++i)
            if (!((got >> i) & 1))
                v[i] = __hip_atomic_load(buf + tid + i * 256, __ATOMIC_RELAXED,
                                         __HIP_MEMORY_SCOPE_AGENT);
        #pragma unroll
        for (int i = 0; i < 30; ++i)
            if (!((got >> i) & 1)) {
                if ((u32)(v[i] >> 32) == tag) {
                    got |= 1u << i;
                    u32 w = tid + (u32)i * 256u;          // 0..7679
                    h_lds[(w >> 9) * LDS_ROW + (w & 511)] = (u32)v[i];
                }
            }
        if (++guard > (1 << 20)) return false;
    }
    return true;
}

__global__ void __launch_bounds__(256, 1) k_scan(
        const float* __restrict__ W_hh, const u64* __restrict__ xp,
        u64* __restrict__ htag,
        const float* __restrict__ W_fc, const float* __restrict__ b_fc,
        float* __restrict__ out) {
    __shared__ u32 h_lds[16 * LDS_ROW];
    __shared__ float red[16 * 16];
    __shared__ int s_dead;

    const int g    = blockIdx.x;
    const int tid  = threadIdx.x;
    const int wave = tid >> 6;
    const int l    = tid & 63;
    const int c    = l & 15;
    const int quad = l >> 4;
    const int col  = g * 64 + wave * 16 + c;   // this lane's output column
    const int cw   = g * 4 + wave;

    // --- load W_hh fragments permanently into registers (128 VGPRs) ---
    short8 wf[32];
    {
        const float* wr = W_hh + (size_t)col * N_H;
        #pragma unroll
        for (int kk = 0; kk < 32; ++kk) {
            const float* p = wr + kk * 32 + quad * 8;
            float4 w0 = *(const float4*)(p);
            float4 w1 = *(const float4*)(p + 4);
            short8 b;
            b[0]=(short)f2bf1(w0.x); b[1]=(short)f2bf1(w0.y); b[2]=(short)f2bf1(w0.z); b[3]=(short)f2bf1(w0.w);
            b[4]=(short)f2bf1(w1.x); b[5]=(short)f2bf1(w1.y); b[6]=(short)f2bf1(w1.z); b[7]=(short)f2bf1(w1.w);
            wf[kk] = b;
        }
    }
    // zero h LDS (h_0 = 0; row 15 pad stays 0 forever)
    for (int i = tid; i < 16 * LDS_ROW; i += 256) h_lds[i] = 0;
    if (tid == 0) s_dead = 0;
    __syncthreads();

    for (int s = 0; s < T_STEPS; ++s) {
        // xp for this step (independent of recurrence -> issues early)
        u64 xpw = xp[((size_t)s * 64 + cw) * 64 + l];

        if (s > 0) {
            const u64* buf = htag + (size_t)(s & 1) * HTAG_WORDS;
            if (!poll_stage(buf, (u32)s, tid, h_lds)) s_dead = 1;
        }
        __syncthreads();
        if (s_dead) break;

        floatx4 acc;
        acc[0] = bf2f((u32)(xpw       ) & 0xFFFFu);
        acc[1] = bf2f((u32)(xpw >> 16 ) & 0xFFFFu);
        acc[2] = bf2f((u32)(xpw >> 32 ) & 0xFFFFu);
        acc[3] = bf2f((u32)(xpw >> 48 ) & 0xFFFFu);

        #pragma unroll
        for (int kk = 0; kk < 32; ++kk) {
            uint4 av = *(const uint4*)&h_lds[c * LDS_ROW + kk * 16 + quad * 4];
            acc = __builtin_amdgcn_mfma_f32_16x16x32_bf16(
                      __builtin_bit_cast(short8, av), wf[kk], acc, 0, 0, 0);
        }

        float h[4];
        #pragma unroll
        for (int i = 0; i < 4; ++i) h[i] = tanh_fast(acc[i]);

        // publish tagged bf16 pairs to buffer (s+1)&1
        u64* buf = htag + (size_t)((s + 1) & 1) * HTAG_WORDS;
        u32 tag1 = (u32)(s + 1);
        #pragma unroll
        for (int i = 0; i < 4; ++i) {
            int b = quad * 4 + i;
            float o = __shfl_xor(h[i], 1);
            if (!(c & 1) && b < 15) {
                u32 data = f2bf1(h[i]) | (f2bf1(o) << 16);
                u64 w = ((u64)tag1 << 32) | (u64)data;
                __hip_atomic_store(buf + b * 512 + (col >> 1), w, __ATOMIC_RELAXED,
                                   __HIP_MEMORY_SCOPE_AGENT);
            }
        }
        __syncthreads();   // LDS reused next iteration; keep waves in step
    }

    // ---------------- epilogue: WG 0 computes the sigmoid head ----------------
    if (g == 0) {
        const u64* buf = htag + (size_t)((T_STEPS) & 1) * HTAG_WORDS;  // parity 0
        poll_stage(buf, (u32)T_STEPS, tid, h_lds);
        __syncthreads();
        if (tid < 240) {
            int b = tid >> 4, seg = tid & 15;
            float sum = 0.f;
            for (int j = 0; j < 64; ++j) {
                int k = seg * 64 + j;
                u32 pr = h_lds[b * LDS_ROW + (k >> 1)];
                float hv = bf2f((pr >> ((k & 1) * 16)) & 0xFFFFu);
                sum += hv * W_fc[k];
            }
            red[tid] = sum;
        }
        __syncthreads();
        if (tid < 15) {
            float z = 0.f;
            #pragma unroll
            for (int j = 0; j < 16; ++j) z += red[tid * 16 + j];
            z += b_fc[0];
            out[tid] = 1.0f / (1.0f + __expf(-z));
        }
    }
}

extern "C" void kernel_launch(void* const* d_in, const int* in_sizes, int n_in,
                              void* d_out, int out_size, void* d_ws, size_t ws_size,
                              hipStream_t stream) {
    const float* x    = (const float*)d_in[0];
    const float* W_ih = (const float*)d_in[1];
    const float* b_ih = (const float*)d_in[2];
    const float* W_hh = (const float*)d_in[3];
    const float* b_hh = (const float*)d_in[4];
    const float* W_fc = (const float*)d_in[5];
    const float* b_fc = (const float*)d_in[6];
    float* out = (float*)d_out;

    char* ws   = (char*)d_ws;
    u64*  xp   = (u64*)(ws + OFF_XP);
    u32*  wihb = (u32*)(ws + OFF_WIHB);
    u64*  htag = (u64*)(ws + OFF_HTAG);

    k_cvt_wih<<<dim3(N_H), dim3(256), 0, stream>>>(W_ih, wihb);
    k_xproj<<<dim3(T_STEPS, 4), dim3(256), 0, stream>>>(x, wihb, b_ih, b_hh, xp);
    k_scan<<<dim3(G_SCAN), dim3(256), 0, stream>>>(W_hh, xp, htag, W_fc, b_fc, out);
}